// Round 1
// baseline (707.577 us; speedup 1.0000x reference)
//
#include <hip/hip_runtime.h>

#define N_NODES 50000
#define EPS 1e-6f

// ---------------- Workspace layout (floats) ----------------
// num1 : N*64    (zeroed each call)
// deg  : N       (zeroed each call)
// h1   : N*128   (fully overwritten)
// num2 : N*128   (zeroed each call)

// Scatter pass 1: num1[dst] += x[src] (64 feats), deg[dst] += 1
__global__ __launch_bounds__(256) void scatter1_kernel(
    const float* __restrict__ x, const int* __restrict__ src,
    const int* __restrict__ dst, float* __restrict__ num1,
    float* __restrict__ deg, int E) {
  int e = blockIdx.x * 4 + (threadIdx.x >> 6);
  int lane = threadIdx.x & 63;
  if (e >= E) return;
  int s = src[e];
  int d = dst[e];
  float v = x[(size_t)s * 64 + lane];
  atomicAdd(&num1[(size_t)d * 64 + lane], v);
  if (lane == 0) atomicAdd(&deg[d], 1.0f);
}

// Scatter pass 2: num2[dst] += h1[src] (128 feats)
__global__ __launch_bounds__(256) void scatter2_kernel(
    const float* __restrict__ h1, const int* __restrict__ src,
    const int* __restrict__ dst, float* __restrict__ num2, int E) {
  int e = blockIdx.x * 2 + (threadIdx.x >> 7);
  int lane = threadIdx.x & 127;
  if (e >= E) return;
  int s = src[e];
  int d = dst[e];
  float v = h1[(size_t)s * 128 + lane];
  atomicAdd(&num2[(size_t)d * 128 + lane], v);
}

// h1 = relu((num1/(deg+eps)) @ W1 + b1)   [N,64]x[64,128]
// 16 rows per block, 256 threads; W1 (32KB) staged in LDS.
__global__ __launch_bounds__(256) void mlp1_kernel(
    const float* __restrict__ num1, const float* __restrict__ deg,
    const float* __restrict__ W1, const float* __restrict__ b1,
    float* __restrict__ h1) {
  __shared__ float sW[64 * 128];   // 32 KB
  __shared__ float sM[16][64];     // 4 KB
  int t = threadIdx.x;
  int row0 = blockIdx.x * 16;

  // Stage W1: 8192 floats = 2048 float4, 8 per thread.
  const float4* W4 = (const float4*)W1;
  float4* sW4 = (float4*)sW;
#pragma unroll
  for (int i = 0; i < 8; i++) sW4[t + 256 * i] = W4[t + 256 * i];

  // Stage means: 16 rows x 64 = 1024 floats = 256 float4, 1 per thread.
  {
    int r = t >> 4;         // 0..15
    int c4 = t & 15;        // 0..15 (x4 floats)
    int row = row0 + r;
    float dinv = 1.0f / (deg[row] + EPS);
    const float4* nrow = (const float4*)(num1 + (size_t)row * 64);
    float4 v = nrow[c4];
    float* dst4 = &sM[r][c4 * 4];
    dst4[0] = v.x * dinv;
    dst4[1] = v.y * dinv;
    dst4[2] = v.z * dinv;
    dst4[3] = v.w * dinv;
  }
  __syncthreads();

  int c = t & 127;          // output col
  int r0 = (t >> 7) * 8;    // 8 rows per thread
  float acc[8];
  float bias = b1[c];
#pragma unroll
  for (int r = 0; r < 8; r++) acc[r] = bias;
  for (int k = 0; k < 64; k++) {
    float w = sW[k * 128 + c];
#pragma unroll
    for (int r = 0; r < 8; r++) acc[r] = fmaf(sM[r0 + r][k], w, acc[r]);
  }
#pragma unroll
  for (int r = 0; r < 8; r++)
    h1[(size_t)(row0 + r0 + r) * 128 + c] = fmaxf(acc[r], 0.0f);
}

// out = log_softmax((num2/(deg+eps)) @ W2 + b2)   [N,128]x[128,64]
// 8 rows per block (one wave per row), 512 threads; W2 (32KB) in LDS.
__global__ __launch_bounds__(512) void mlp2_kernel(
    const float* __restrict__ num2, const float* __restrict__ deg,
    const float* __restrict__ W2, const float* __restrict__ b2,
    float* __restrict__ out) {
  __shared__ float sW[128 * 64];   // 32 KB
  __shared__ float sM[8][128];     // 4 KB
  int t = threadIdx.x;
  int row0 = blockIdx.x * 8;

  // Stage W2: 8192 floats = 2048 float4, 4 per thread.
  const float4* W4 = (const float4*)W2;
  float4* sW4 = (float4*)sW;
#pragma unroll
  for (int i = 0; i < 4; i++) sW4[t + 512 * i] = W4[t + 512 * i];

  // Stage means: 8 rows x 128 = 1024 floats, 2 per thread.
#pragma unroll
  for (int i = 0; i < 2; i++) {
    int j = t + i * 512;
    int r = j >> 7, k = j & 127;
    int row = row0 + r;
    sM[r][k] = num2[(size_t)row * 128 + k] / (deg[row] + EPS);
  }
  __syncthreads();

  int wave = t >> 6;        // 0..7 -> row
  int lane = t & 63;        // output col
  int row = row0 + wave;
  float acc = b2[lane];
  for (int k = 0; k < 128; k++)
    acc = fmaf(sM[wave][k], sW[k * 64 + lane], acc);

  // log_softmax across the 64 lanes (one row per wave)
  float mx = acc;
#pragma unroll
  for (int off = 32; off > 0; off >>= 1)
    mx = fmaxf(mx, __shfl_xor(mx, off, 64));
  float ex = __expf(acc - mx);
  float sm = ex;
#pragma unroll
  for (int off = 32; off > 0; off >>= 1)
    sm += __shfl_xor(sm, off, 64);
  out[(size_t)row * 64 + lane] = (acc - mx) - logf(sm);
}

extern "C" void kernel_launch(void* const* d_in, const int* in_sizes, int n_in,
                              void* d_out, int out_size, void* d_ws, size_t ws_size,
                              hipStream_t stream) {
  const float* x   = (const float*)d_in[0];
  const int*   src = (const int*)d_in[1];
  const int*   dst = (const int*)d_in[2];
  const float* W1  = (const float*)d_in[3];
  const float* b1  = (const float*)d_in[4];
  const float* W2  = (const float*)d_in[5];
  const float* b2  = (const float*)d_in[6];
  float* out = (float*)d_out;
  int E = in_sizes[1];

  float* num1 = (float*)d_ws;                          // N*64
  float* deg  = num1 + (size_t)N_NODES * 64;           // N
  float* h1   = deg + N_NODES;                         // N*128
  float* num2 = h1 + (size_t)N_NODES * 128;            // N*128

  hipMemsetAsync(num1, 0, (size_t)N_NODES * 64 * sizeof(float), stream);
  hipMemsetAsync(deg,  0, (size_t)N_NODES * sizeof(float), stream);
  hipMemsetAsync(num2, 0, (size_t)N_NODES * 128 * sizeof(float), stream);

  scatter1_kernel<<<(E + 3) / 4, 256, 0, stream>>>(x, src, dst, num1, deg, E);
  mlp1_kernel<<<N_NODES / 16, 256, 0, stream>>>(num1, deg, W1, b1, h1);
  scatter2_kernel<<<(E + 1) / 2, 256, 0, stream>>>(h1, src, dst, num2, E);
  mlp2_kernel<<<N_NODES / 8, 512, 0, stream>>>(num2, deg, W2, b2, out);
}

// Round 2
// 452.377 us; speedup vs baseline: 1.5641x; 1.5641x over previous
//
#include <hip/hip_runtime.h>

#define N_NODES 50000
#define EPS 1e-6f

// ---------------- Workspace layout ----------------
// cnt    : N ints (padded 50176)  -- zeroed each call, degree histogram
// off    : N+1 ints (padded 50176)-- CSR row offsets
// cursor : N ints (padded 50176)  -- fill cursors
// ssrc   : E ints                 -- src ids sorted by dst
// meanA  : N*128 floats           -- mean1 uses first N*64; mean2 uses all (mean1 dead by then)
// h1     : N*128 floats

// ---- CSR build ----
__global__ __launch_bounds__(256) void hist_kernel(
    const int* __restrict__ dst, int* __restrict__ cnt, int E) {
  int e = blockIdx.x * 256 + threadIdx.x;
  if (e < E) atomicAdd(&cnt[dst[e]], 1);
}

// Single-block exclusive scan of cnt[0..N) -> off[0..N], cursor[0..N)
__global__ __launch_bounds__(1024) void scan_kernel(
    const int* __restrict__ cnt, int* __restrict__ off,
    int* __restrict__ cursor) {
  __shared__ int buf[2][1024];
  int t = threadIdx.x;
  const int C = 49;  // 1024*49 = 50176 >= N
  int begin = t * C;
  int end = begin + C; if (end > N_NODES) end = N_NODES;
  int s = 0;
  for (int i = begin; i < end && i < N_NODES; i++) s += cnt[i];
  buf[0][t] = s;
  __syncthreads();
  int cur = 0;
  for (int d = 1; d < 1024; d <<= 1) {
    int v = buf[cur][t];
    if (t >= d) v += buf[cur][t - d];
    buf[cur ^ 1][t] = v;
    __syncthreads();
    cur ^= 1;
  }
  int run = buf[cur][t] - s;  // exclusive prefix of this chunk
  for (int i = begin; i < end && i < N_NODES; i++) {
    int c = cnt[i];
    off[i] = run;
    cursor[i] = run;
    run += c;
  }
  if (t == 1023) off[N_NODES] = buf[cur][1023];
}

__global__ __launch_bounds__(256) void fill_kernel(
    const int* __restrict__ src, const int* __restrict__ dst,
    int* __restrict__ cursor, int* __restrict__ ssrc, int E) {
  int e = blockIdx.x * 256 + threadIdx.x;
  if (e < E) {
    int pos = atomicAdd(&cursor[dst[e]], 1);
    ssrc[pos] = src[e];
  }
}

// ---- Aggregation pass 1: mean1[n] = mean of x[neighbors], 64 feats, 1 wave/node ----
__global__ __launch_bounds__(256) void gather1_kernel(
    const float* __restrict__ x, const int* __restrict__ off,
    const int* __restrict__ ssrc, float* __restrict__ mean1) {
  int node = blockIdx.x * 4 + (threadIdx.x >> 6);
  int lane = threadIdx.x & 63;
  if (node >= N_NODES) return;
  int b = off[node], eN = off[node + 1];
  float acc = 0.0f;
  for (int base = b; base < eN; base += 64) {
    int m = eN - base; if (m > 64) m = 64;
    int idx = (lane < m) ? ssrc[base + lane] : 0;  // one coalesced load
    for (int j = 0; j < m; j++) {
      int s = __shfl(idx, j, 64);
      acc += x[(size_t)s * 64 + lane];
    }
  }
  float dinv = 1.0f / ((float)(eN - b) + EPS);
  mean1[(size_t)node * 64 + lane] = acc * dinv;
}

// ---- Aggregation pass 2: mean2[n] = mean of h1[neighbors], 128 feats, 1 wave/node ----
__global__ __launch_bounds__(256) void gather2_kernel(
    const float* __restrict__ h1, const int* __restrict__ off,
    const int* __restrict__ ssrc, float* __restrict__ mean2) {
  int node = blockIdx.x * 4 + (threadIdx.x >> 6);
  int lane = threadIdx.x & 63;
  if (node >= N_NODES) return;
  int b = off[node], eN = off[node + 1];
  float ax = 0.0f, ay = 0.0f;
  for (int base = b; base < eN; base += 64) {
    int m = eN - base; if (m > 64) m = 64;
    int idx = (lane < m) ? ssrc[base + lane] : 0;
    for (int j = 0; j < m; j++) {
      int s = __shfl(idx, j, 64);
      float2 v = ((const float2*)(h1 + (size_t)s * 128))[lane];
      ax += v.x; ay += v.y;
    }
  }
  float dinv = 1.0f / ((float)(eN - b) + EPS);
  float2 o; o.x = ax * dinv; o.y = ay * dinv;
  ((float2*)(mean2 + (size_t)node * 128))[lane] = o;
}

// h1 = relu(mean1 @ W1 + b1)   [N,64]x[64,128]
__global__ __launch_bounds__(256) void mlp1_kernel(
    const float* __restrict__ mean1, const float* __restrict__ W1,
    const float* __restrict__ b1, float* __restrict__ h1) {
  __shared__ float sW[64 * 128];   // 32 KB
  __shared__ float sM[16][64];     // 4 KB
  int t = threadIdx.x;
  int row0 = blockIdx.x * 16;

  const float4* W4 = (const float4*)W1;
  float4* sW4 = (float4*)sW;
#pragma unroll
  for (int i = 0; i < 8; i++) sW4[t + 256 * i] = W4[t + 256 * i];

  {
    int r = t >> 4, c4 = t & 15;
    int row = row0 + r;
    float4 v = ((const float4*)(mean1 + (size_t)row * 64))[c4];
    float* d4 = &sM[r][c4 * 4];
    d4[0] = v.x; d4[1] = v.y; d4[2] = v.z; d4[3] = v.w;
  }
  __syncthreads();

  int c = t & 127;
  int r0 = (t >> 7) * 8;
  float acc[8];
  float bias = b1[c];
#pragma unroll
  for (int r = 0; r < 8; r++) acc[r] = bias;
  for (int k = 0; k < 64; k++) {
    float w = sW[k * 128 + c];
#pragma unroll
    for (int r = 0; r < 8; r++) acc[r] = fmaf(sM[r0 + r][k], w, acc[r]);
  }
#pragma unroll
  for (int r = 0; r < 8; r++)
    h1[(size_t)(row0 + r0 + r) * 128 + c] = fmaxf(acc[r], 0.0f);
}

// out = log_softmax(mean2 @ W2 + b2)   [N,128]x[128,64]
__global__ __launch_bounds__(512) void mlp2_kernel(
    const float* __restrict__ mean2, const float* __restrict__ W2,
    const float* __restrict__ b2, float* __restrict__ out) {
  __shared__ float sW[128 * 64];   // 32 KB
  __shared__ float sM[8][128];     // 4 KB
  int t = threadIdx.x;
  int row0 = blockIdx.x * 8;

  const float4* W4 = (const float4*)W2;
  float4* sW4 = (float4*)sW;
#pragma unroll
  for (int i = 0; i < 4; i++) sW4[t + 512 * i] = W4[t + 512 * i];

#pragma unroll
  for (int i = 0; i < 2; i++) {
    int j = t + i * 512;
    int r = j >> 7, k = j & 127;
    sM[r][k] = mean2[(size_t)(row0 + r) * 128 + k];
  }
  __syncthreads();

  int wave = t >> 6;
  int lane = t & 63;
  int row = row0 + wave;
  float acc = b2[lane];
  for (int k = 0; k < 128; k++)
    acc = fmaf(sM[wave][k], sW[k * 64 + lane], acc);

  float mx = acc;
#pragma unroll
  for (int off = 32; off > 0; off >>= 1)
    mx = fmaxf(mx, __shfl_xor(mx, off, 64));
  float ex = __expf(acc - mx);
  float sm = ex;
#pragma unroll
  for (int off = 32; off > 0; off >>= 1)
    sm += __shfl_xor(sm, off, 64);
  out[(size_t)row * 64 + lane] = (acc - mx) - logf(sm);
}

extern "C" void kernel_launch(void* const* d_in, const int* in_sizes, int n_in,
                              void* d_out, int out_size, void* d_ws, size_t ws_size,
                              hipStream_t stream) {
  const float* x   = (const float*)d_in[0];
  const int*   src = (const int*)d_in[1];
  const int*   dst = (const int*)d_in[2];
  const float* W1  = (const float*)d_in[3];
  const float* b1  = (const float*)d_in[4];
  const float* W2  = (const float*)d_in[5];
  const float* b2  = (const float*)d_in[6];
  float* out = (float*)d_out;
  int E = in_sizes[1];

  const int PAD = 50176;  // 1024*49
  int* cnt    = (int*)d_ws;
  int* off    = cnt + PAD;
  int* cursor = off + PAD;
  int* ssrc   = cursor + PAD;
  float* meanA = (float*)(ssrc + 800000);       // N*128 floats (mean1 = first N*64)
  float* h1    = meanA + (size_t)N_NODES * 128;
  float* mean1 = meanA;
  float* mean2 = meanA;

  hipMemsetAsync(cnt, 0, (size_t)N_NODES * sizeof(int), stream);
  hist_kernel<<<(E + 255) / 256, 256, 0, stream>>>(dst, cnt, E);
  scan_kernel<<<1, 1024, 0, stream>>>(cnt, off, cursor);
  fill_kernel<<<(E + 255) / 256, 256, 0, stream>>>(src, dst, cursor, ssrc, E);

  gather1_kernel<<<(N_NODES + 3) / 4, 256, 0, stream>>>(x, off, ssrc, mean1);
  mlp1_kernel<<<N_NODES / 16, 256, 0, stream>>>(mean1, W1, b1, h1);
  gather2_kernel<<<(N_NODES + 3) / 4, 256, 0, stream>>>(h1, off, ssrc, mean2);
  mlp2_kernel<<<N_NODES / 8, 512, 0, stream>>>(mean2, W2, b2, out);
}

// Round 3
// 277.058 us; speedup vs baseline: 2.5539x; 1.6328x over previous
//
#include <hip/hip_runtime.h>

#define N_NODES 50000
#define EPS 1e-6f
#define SCAN_BLOCKS 196   // 196*256 = 50176 >= N_NODES

// ---------------- Workspace layout ----------------
// cnt    : 50176 ints  (zeroed each call)
// off    : 50176 ints  (off[N] = E total)
// cursor : 50176 ints
// bsum   : 256 ints    (per-block sums / exclusive block offsets)
// ssrc   : E ints      (src ids grouped by dst)
// mean1  : N*64  floats
// h1     : N*128 floats
// g      : N*64  floats  (h1 @ W2, pre-gather)

// ---- CSR build ----
__global__ __launch_bounds__(256) void hist_kernel(
    const int* __restrict__ dst, int* __restrict__ cnt, int E) {
  int e = blockIdx.x * 256 + threadIdx.x;
  if (e < E) atomicAdd(&cnt[dst[e]], 1);
}

// Phase 1: per-block (256-elem) sums
__global__ __launch_bounds__(256) void scan1_kernel(
    const int* __restrict__ cnt, int* __restrict__ bsum) {
  __shared__ int red[4];
  int t = threadIdx.x;
  int i = blockIdx.x * 256 + t;
  int v = (i < N_NODES) ? cnt[i] : 0;
#pragma unroll
  for (int o = 32; o > 0; o >>= 1) v += __shfl_xor(v, o, 64);
  if ((t & 63) == 0) red[t >> 6] = v;
  __syncthreads();
  if (t == 0) bsum[blockIdx.x] = red[0] + red[1] + red[2] + red[3];
}

// Phase 2: single block scans the 196 block sums -> exclusive block offsets
__global__ __launch_bounds__(256) void scan2_kernel(
    int* __restrict__ bsum, int* __restrict__ off) {
  __shared__ int wsum[4];
  int t = threadIdx.x;
  int v = (t < SCAN_BLOCKS) ? bsum[t] : 0;
  int lane = t & 63, wv = t >> 6;
  int x = v;
#pragma unroll
  for (int d = 1; d < 64; d <<= 1) {
    int y = __shfl_up(x, d, 64);
    if (lane >= d) x += y;
  }
  if (lane == 63) wsum[wv] = x;
  __syncthreads();
  int add = 0;
  for (int w = 0; w < wv; w++) add += wsum[w];
  x += add;                       // inclusive scan
  if (t < SCAN_BLOCKS) bsum[t] = x - v;  // exclusive
  if (t == SCAN_BLOCKS - 1) off[N_NODES] = x;  // total = E
}

// Phase 3: per-block local scan + block offset -> off, cursor
__global__ __launch_bounds__(256) void scan3_kernel(
    const int* __restrict__ cnt, const int* __restrict__ bsum,
    int* __restrict__ off, int* __restrict__ cursor) {
  __shared__ int wsum[4];
  int t = threadIdx.x;
  int i = blockIdx.x * 256 + t;
  int v = (i < N_NODES) ? cnt[i] : 0;
  int lane = t & 63, wv = t >> 6;
  int x = v;
#pragma unroll
  for (int d = 1; d < 64; d <<= 1) {
    int y = __shfl_up(x, d, 64);
    if (lane >= d) x += y;
  }
  if (lane == 63) wsum[wv] = x;
  __syncthreads();
  int add = bsum[blockIdx.x];
  for (int w = 0; w < wv; w++) add += wsum[w];
  int excl = add + x - v;
  if (i < N_NODES) {
    off[i] = excl;
    cursor[i] = excl;
  }
}

__global__ __launch_bounds__(256) void fill_kernel(
    const int* __restrict__ src, const int* __restrict__ dst,
    int* __restrict__ cursor, int* __restrict__ ssrc, int E) {
  int e = blockIdx.x * 256 + threadIdx.x;
  if (e < E) {
    int pos = atomicAdd(&cursor[dst[e]], 1);
    ssrc[pos] = src[e];
  }
}

// ---- Aggregation pass 1: mean1[n] = mean of x[neighbors], 64 feats, 1 wave/node ----
__global__ __launch_bounds__(256) void gather1_kernel(
    const float* __restrict__ x, const int* __restrict__ off,
    const int* __restrict__ ssrc, float* __restrict__ mean1) {
  int node = blockIdx.x * 4 + (threadIdx.x >> 6);
  int lane = threadIdx.x & 63;
  if (node >= N_NODES) return;
  int b = off[node], e = off[node + 1];
  float acc = 0.0f;
  for (int base = b; base < e; base += 64) {
    int m = e - base; if (m > 64) m = 64;
    int idx = (lane < m) ? ssrc[base + lane] : 0;
    int j = 0;
    for (; j + 4 <= m; j += 4) {
      int s0 = __shfl(idx, j, 64);
      int s1 = __shfl(idx, j + 1, 64);
      int s2 = __shfl(idx, j + 2, 64);
      int s3 = __shfl(idx, j + 3, 64);
      float v0 = x[(size_t)s0 * 64 + lane];
      float v1 = x[(size_t)s1 * 64 + lane];
      float v2 = x[(size_t)s2 * 64 + lane];
      float v3 = x[(size_t)s3 * 64 + lane];
      acc += (v0 + v1) + (v2 + v3);
    }
    for (; j < m; j++) {
      int s = __shfl(idx, j, 64);
      acc += x[(size_t)s * 64 + lane];
    }
  }
  float dinv = 1.0f / ((float)(e - b) + EPS);
  mean1[(size_t)node * 64 + lane] = acc * dinv;
}

// h1 = relu(mean1 @ W1 + b1)   [N,64]x[64,128]
__global__ __launch_bounds__(256) void mlp1_kernel(
    const float* __restrict__ mean1, const float* __restrict__ W1,
    const float* __restrict__ b1, float* __restrict__ h1) {
  __shared__ float sW[64 * 128];   // 32 KB
  __shared__ float sM[16][64];     // 4 KB
  int t = threadIdx.x;
  int row0 = blockIdx.x * 16;

  const float4* W4 = (const float4*)W1;
  float4* sW4 = (float4*)sW;
#pragma unroll
  for (int i = 0; i < 8; i++) sW4[t + 256 * i] = W4[t + 256 * i];

  {
    int r = t >> 4, c4 = t & 15;
    int row = row0 + r;
    float4 v = ((const float4*)(mean1 + (size_t)row * 64))[c4];
    float* d4 = &sM[r][c4 * 4];
    d4[0] = v.x; d4[1] = v.y; d4[2] = v.z; d4[3] = v.w;
  }
  __syncthreads();

  int c = t & 127;
  int r0 = (t >> 7) * 8;
  float acc[8];
  float bias = b1[c];
#pragma unroll
  for (int r = 0; r < 8; r++) acc[r] = bias;
  for (int k = 0; k < 64; k++) {
    float w = sW[k * 128 + c];
#pragma unroll
    for (int r = 0; r < 8; r++) acc[r] = fmaf(sM[r0 + r][k], w, acc[r]);
  }
#pragma unroll
  for (int r = 0; r < 8; r++)
    h1[(size_t)(row0 + r0 + r) * 128 + c] = fmaxf(acc[r], 0.0f);
}

// g = h1 @ W2 (no bias)   [N,128]x[128,64]
__global__ __launch_bounds__(256) void mlp2a_kernel(
    const float* __restrict__ h1, const float* __restrict__ W2,
    float* __restrict__ g) {
  __shared__ float sW[128 * 64];   // 32 KB
  __shared__ float sM[16][128];    // 8 KB
  int t = threadIdx.x;
  int row0 = blockIdx.x * 16;

  const float4* W4 = (const float4*)W2;
  float4* sW4 = (float4*)sW;
#pragma unroll
  for (int i = 0; i < 8; i++) sW4[t + 256 * i] = W4[t + 256 * i];

  // Stage 16 rows x 128 = 2048 floats = 512 float4, 2 per thread.
  const float4* H4 = (const float4*)(h1 + (size_t)row0 * 128);
  float4* sM4 = (float4*)sM;
#pragma unroll
  for (int i = 0; i < 2; i++) sM4[t + 256 * i] = H4[t + 256 * i];
  __syncthreads();

  int c = t & 63;           // output col
  int r0 = (t >> 6) * 4;    // 4 rows per thread
  float acc[4] = {0.f, 0.f, 0.f, 0.f};
  for (int k = 0; k < 128; k++) {
    float w = sW[k * 64 + c];
#pragma unroll
    for (int r = 0; r < 4; r++) acc[r] = fmaf(sM[r0 + r][k], w, acc[r]);
  }
#pragma unroll
  for (int r = 0; r < 4; r++)
    g[(size_t)(row0 + r0 + r) * 64 + c] = acc[r];
}

// Fused: out[n] = log_softmax(mean of g[neighbors] + b2), 64 feats, 1 wave/node
__global__ __launch_bounds__(256) void gather2_kernel(
    const float* __restrict__ g, const int* __restrict__ off,
    const int* __restrict__ ssrc, const float* __restrict__ b2,
    float* __restrict__ out) {
  int node = blockIdx.x * 4 + (threadIdx.x >> 6);
  int lane = threadIdx.x & 63;
  if (node >= N_NODES) return;
  int b = off[node], e = off[node + 1];
  float acc = 0.0f;
  for (int base = b; base < e; base += 64) {
    int m = e - base; if (m > 64) m = 64;
    int idx = (lane < m) ? ssrc[base + lane] : 0;
    int j = 0;
    for (; j + 4 <= m; j += 4) {
      int s0 = __shfl(idx, j, 64);
      int s1 = __shfl(idx, j + 1, 64);
      int s2 = __shfl(idx, j + 2, 64);
      int s3 = __shfl(idx, j + 3, 64);
      float v0 = g[(size_t)s0 * 64 + lane];
      float v1 = g[(size_t)s1 * 64 + lane];
      float v2 = g[(size_t)s2 * 64 + lane];
      float v3 = g[(size_t)s3 * 64 + lane];
      acc += (v0 + v1) + (v2 + v3);
    }
    for (; j < m; j++) {
      int s = __shfl(idx, j, 64);
      acc += g[(size_t)s * 64 + lane];
    }
  }
  float dinv = 1.0f / ((float)(e - b) + EPS);
  float val = acc * dinv + b2[lane];

  float mx = val;
#pragma unroll
  for (int o = 32; o > 0; o >>= 1)
    mx = fmaxf(mx, __shfl_xor(mx, o, 64));
  float ex = __expf(val - mx);
  float sm = ex;
#pragma unroll
  for (int o = 32; o > 0; o >>= 1)
    sm += __shfl_xor(sm, o, 64);
  out[(size_t)node * 64 + lane] = (val - mx) - logf(sm);
}

extern "C" void kernel_launch(void* const* d_in, const int* in_sizes, int n_in,
                              void* d_out, int out_size, void* d_ws, size_t ws_size,
                              hipStream_t stream) {
  const float* x   = (const float*)d_in[0];
  const int*   src = (const int*)d_in[1];
  const int*   dst = (const int*)d_in[2];
  const float* W1  = (const float*)d_in[3];
  const float* b1  = (const float*)d_in[4];
  const float* W2  = (const float*)d_in[5];
  const float* b2  = (const float*)d_in[6];
  float* out = (float*)d_out;
  int E = in_sizes[1];

  const int PAD = 50176;  // SCAN_BLOCKS*256
  int* cnt    = (int*)d_ws;
  int* off    = cnt + PAD;
  int* cursor = off + PAD;
  int* bsum   = cursor + PAD;           // 256 ints
  int* ssrc   = bsum + 256;
  float* mean1 = (float*)(ssrc + 800000);
  float* h1    = mean1 + (size_t)N_NODES * 64;
  float* g     = h1 + (size_t)N_NODES * 128;

  hipMemsetAsync(cnt, 0, (size_t)N_NODES * sizeof(int), stream);
  hist_kernel<<<(E + 255) / 256, 256, 0, stream>>>(dst, cnt, E);
  scan1_kernel<<<SCAN_BLOCKS, 256, 0, stream>>>(cnt, bsum);
  scan2_kernel<<<1, 256, 0, stream>>>(bsum, off);
  scan3_kernel<<<SCAN_BLOCKS, 256, 0, stream>>>(cnt, bsum, off, cursor);
  fill_kernel<<<(E + 255) / 256, 256, 0, stream>>>(src, dst, cursor, ssrc, E);

  gather1_kernel<<<(N_NODES + 3) / 4, 256, 0, stream>>>(x, off, ssrc, mean1);
  mlp1_kernel<<<N_NODES / 16, 256, 0, stream>>>(mean1, W1, b1, h1);
  mlp2a_kernel<<<N_NODES / 16, 256, 0, stream>>>(h1, W2, g);
  gather2_kernel<<<(N_NODES + 3) / 4, 256, 0, stream>>>(g, off, ssrc, b2, out);
}